// Round 3
// baseline (274.114 us; speedup 1.0000x reference)
//
#include <hip/hip_runtime.h>

typedef unsigned short u16;
typedef __bf16 bf16x8 __attribute__((ext_vector_type(8)));
typedef float f32x4 __attribute__((ext_vector_type(4)));

// Problem constants (from reference)
#define NB 16      // batches
#define NC 64      // channels
#define NK 207     // nodes (K_DIM)
#define NL 64      // time (L_DIM)
#define KP 224     // padded GEMM K-dim over nodes (207 -> 224 = 7*32)
#define NKL 13248  // NK*NL
#define GROWS 1152 // stacked-G rows: 5*208 + 112 pad
#define CIN 320

__device__ __forceinline__ u16 f2bf(float f) {
  unsigned u = __builtin_bit_cast(unsigned, f);
  u += 0x7FFFu + ((u >> 16) & 1u);   // RNE; inputs are never NaN
  return (u16)(u >> 16);
}

// async global->LDS, 16 B per lane. ldst must be (wave-uniform base + lane*16).
__device__ __forceinline__ void g2l16(const u16* gsrc, u16* ldst) {
  __builtin_amdgcn_global_load_lds(
      (const __attribute__((address_space(1))) unsigned int*)gsrc,
      (__attribute__((address_space(3))) unsigned int*)ldst, 16, 0, 0);
}

// ---------------- prep: x (B,C,K*L) fp32 -> xT[b][(l*64+c)][k0..223] bf16 ----
#define XPAD 225   // odd fp32 stride: conflict-free column writes
__global__ __launch_bounds__(256) void k_prep_x(const float* __restrict__ x,
                                                u16* __restrict__ xT) {
  // grid (64 c, 16 b), 256 threads; one (b,c) plane per block
  int c = blockIdx.x, b = blockIdx.y;
  __shared__ float lds[64 * XPAD];
  const float* xp = x + (size_t)(b * 64 + c) * NKL;
  int t = threadIdx.x;
  for (int i = t; i < NKL; i += 256) {        // coalesced fp32 read
    int k = i >> 6, l = i & 63;
    lds[l * XPAD + k] = xp[i];
  }
  __syncthreads();
  for (int ch = t; ch < 64 * 28; ch += 256) { // 28 int4 chunks per l-row
    int l = ch / 28, kc = ch - l * 28;
    u16 v[8] __attribute__((aligned(16)));
    for (int j = 0; j < 8; j++) {
      int k = kc * 8 + j;
      float f = (k < NK) ? lds[l * XPAD + k] : 0.f;
      v[j] = f2bf(f);
    }
    *(int4*)(xT + ((size_t)b * 4096 + (size_t)l * 64 + c) * KP + kc * 8) = *(int4*)v;
  }
}

// ---- prep: A -> Abf (row-major), AbfT (transposed), G blocks q=1,3 (plain A)
__global__ void k_prep_A(const float* __restrict__ a0, const float* __restrict__ a1,
                         u16* __restrict__ Abf, u16* __restrict__ AbfT,
                         u16* __restrict__ G) {
  // grid (8 rowtile, 2 w, 16 b), 256 threads
  int rt = blockIdx.x, w = blockIdx.y, b = blockIdx.z;
  const float* A = (w ? a1 : a0) + (size_t)b * NK * NK;
  __shared__ float lds[32][225];
  int t = threadIdx.x;
  int m0 = rt * 32;
  for (int idx = t; idx < 32 * KP; idx += 256) {
    int r = idx / KP, k = idx - r * KP;
    int m = m0 + r;
    float v = (m < NK && k < NK) ? A[m * NK + k] : 0.f;
    lds[r][k] = v;
    u16 bf = f2bf(v);
    Abf[(((size_t)b * 2 + w) * 256 + m) * KP + k] = bf;
    if (m < 208) G[((size_t)b * GROWS + (1 + 2 * w) * 208 + m) * KP + k] = bf;
  }
  __syncthreads();
  if (rt < 7) {
    for (int idx = t; idx < KP * 32; idx += 256) {
      int k = idx >> 5, mm = idx & 31;
      AbfT[(((size_t)b * 2 + w) * 256 + k) * KP + m0 + mm] = f2bf(lds[mm][k]);
    }
  }
}

// ---- prep: identity block, zero pads, W->bf16 -------------------------------
__global__ void k_prep_I(const float* __restrict__ W, u16* __restrict__ G,
                         u16* __restrict__ AbfT, u16* __restrict__ Wbf) {
  // grid (416, 16)
  int b = blockIdx.y;
  int idx = blockIdx.x * 256 + threadIdx.x;
  if (idx < 46592) {                       // G block q=0: identity, rows 0..207
    int j = idx / KP, k = idx - j * KP;
    G[((size_t)b * GROWS + j) * KP + k] = (j == k && j < NK) ? (u16)0x3F80 : (u16)0;
  } else if (idx < 71680) {                // G rows 1040..1151 -> 0
    int r = idx - 46592;
    G[(size_t)b * GROWS * KP + 1040 * KP + r] = 0;
  } else if (idx < 86016) {                // AbfT rows 224..255 -> 0 (both w)
    int r = idx - 71680;
    int w = r / 7168, rr = r - w * 7168;
    AbfT[(((size_t)b * 2 + w) * 256 + 224) * KP + rr] = 0;
  } else if (b == 0) {                     // W convert (once)
    int r = idx - 86016;
    if (r < 64 * CIN) Wbf[r] = f2bf(W[r]);
  }
}

// ---- prep: A^2 via MFMA -> G blocks q=2,4 ----------------------------------
__global__ void k_asq(const u16* __restrict__ Abf, const u16* __restrict__ AbfT,
                      u16* __restrict__ G) {
  // grid (4 ntile, 4 mtile, 32=b*2+w), 256 threads, waves 2x2, wave tile 32x32
  int b = blockIdx.z >> 1, w = blockIdx.z & 1;
  int lane = threadIdx.x & 63, wave = threadIdx.x >> 6;
  int wm = wave >> 1, wn = wave & 1;
  const u16* Ab = Abf + ((size_t)b * 2 + w) * 256 * KP;
  const u16* At = AbfT + ((size_t)b * 2 + w) * 256 * KP;
  int m0 = blockIdx.y * 64 + wm * 32;
  int n0 = blockIdx.x * 64 + wn * 32;
  int r = lane & 15, q = lane >> 4;
  f32x4 acc[2][2] = {};
  for (int k0 = 0; k0 < KP; k0 += 32) {
    bf16x8 af[2], bg[2];
    for (int i = 0; i < 2; i++)
      af[i] = *(const bf16x8*)(Ab + (size_t)(m0 + i * 16 + r) * KP + k0 + q * 8);
    for (int i = 0; i < 2; i++)
      bg[i] = *(const bf16x8*)(At + (size_t)(n0 + i * 16 + r) * KP + k0 + q * 8);
    for (int i = 0; i < 2; i++)
      for (int j = 0; j < 2; j++)
        acc[i][j] = __builtin_amdgcn_mfma_f32_16x16x32_bf16(af[i], bg[j], acc[i][j], 0, 0, 0);
  }
  int qblk = 2 + 2 * w;
  for (int i = 0; i < 2; i++)
    for (int j = 0; j < 2; j++)
      for (int rr = 0; rr < 4; rr++) {
        int mj = m0 + i * 16 + q * 4 + rr;
        int nk = n0 + j * 16 + r;
        if (mj < 208 && nk < KP)
          G[((size_t)b * GROWS + qblk * 208 + mj) * KP + nk] = f2bf(acc[i][j][rr]);
      }
}

// ---- fused: per block (j-tile 64) x (l-tile 4 * all c) x batch -------------
// GEMM-1 (per q, transposed): C1[(l,c)][j'] = sum_k xT[(l,c)][k] G[q*208+J0+j'][k]
// RT: C1 -> B2 LDS (bf16) in B-fragment layout rows n2=(j'*4+lt), k2=c
// GEMM-2: y[o][n2] += sum_c W[o][q*64+c] B2[n2][c]
__global__ __launch_bounds__(256) void k_fused(const u16* __restrict__ G,
                                               const u16* __restrict__ xT,
                                               const u16* __restrict__ Wbf,
                                               const float* __restrict__ bias,
                                               float* __restrict__ y) {
  // 1-D grid of 1024; XCD-grouping swizzle: all 16 l-tiles of a (jt,b) group
  // share id&7 so their partial y lines merge in one XCD's L2.
  int id = blockIdx.x;
  int xcd = id & 7, s = id >> 3;
  int nt = s & 15, g = s >> 4;       // nt: l-tile, g in [0,8)
  int group = g * 8 + xcd;           // [0,64)
  int jt = group & 3, b = group >> 2;
  int l0 = nt * 4, J0 = jt * 64;

  int lane = threadIdx.x & 63, wave = threadIdx.x >> 6;
  int wm = wave >> 1, wn = wave & 1;
  int r = lane & 15, q4 = lane >> 4;

  const u16* Gb = G + (size_t)b * GROWS * KP;
  const u16* Xb = xT + ((size_t)b * 4096 + (size_t)l0 * 64) * KP;

  __shared__ __align__(16) u16 lds[20 * 512 + 16 * 1024];  // 20KB stage + 32KB B2
  u16* B2 = lds + 20 * 512;

  // staging: 20 frag-tiles (16 xT rows-tiles + 4 G row-tiles), 5 per wave
  const u16* src[5];
  u16* dst[5];
  bool isG[5];
  for (int i = 0; i < 5; i++) {
    int t = wave * 5 + i;
    dst[i] = &lds[t * 512 + lane * 8];
    isG[i] = (t >= 16);
    src[i] = isG[i] ? Gb + (size_t)(J0 + (t - 16) * 16 + r) * KP + q4 * 8
                    : Xb + (size_t)(t * 16 + r) * KP + q4 * 8;
  }

  f32x4 acc2[2][8] = {};
  for (int q = 0; q < 5; q++) {
    size_t gq = (size_t)q * 208 * KP;
    f32x4 acc1[8][2] = {};
    for (int k0 = 0; k0 < KP; k0 += 32) {
      for (int i = 0; i < 5; i++)
        g2l16(src[i] + k0 + (isG[i] ? gq : 0), dst[i]);
      __syncthreads();
      bf16x8 af[8], bg[2];
      for (int i = 0; i < 8; i++)
        af[i] = *(const bf16x8*)(&lds[(wm * 8 + i) * 512 + lane * 8]);
      for (int j = 0; j < 2; j++)
        bg[j] = *(const bf16x8*)(&lds[(16 + wn * 2 + j) * 512 + lane * 8]);
      for (int i = 0; i < 8; i++)
        for (int j = 0; j < 2; j++)
          acc1[i][j] = __builtin_amdgcn_mfma_f32_16x16x32_bf16(af[i], bg[j], acc1[i][j], 0, 0, 0);
      __syncthreads();
    }
    // RT: acc1 -> B2. lane holds (l_t, c0+rr) in regs, j' in lane index.
    for (int i = 0; i < 8; i++) {
      int l_t = wm * 2 + (i >> 2);
      int c0 = (i & 3) * 16 + q4 * 4;
      for (int j = 0; j < 2; j++) {
        int jp = wn * 32 + j * 16 + r;
        int n2 = jp * 4 + l_t;
        u16 v[4] __attribute__((aligned(8)));
        for (int rr = 0; rr < 4; rr++) v[rr] = f2bf(acc1[i][j][rr]);
        *(unsigned long long*)(&B2[(((n2 >> 4) * 2 + (c0 >> 5)) << 9) +
                                   ((((c0 & 31) >> 3) * 16 + (n2 & 15)) << 3) +
                                   (c0 & 7)]) = *(unsigned long long*)v;
      }
    }
    __syncthreads();
    // GEMM-2: W a-frags straight from global (L1-hot, 40KB total)
    for (int ks = 0; ks < 2; ks++) {
      bf16x8 aW[2], bB[8];
      for (int i2 = 0; i2 < 2; i2++)
        aW[i2] = *(const bf16x8*)(Wbf + (size_t)(wm * 32 + i2 * 16 + r) * CIN +
                                  q * 64 + ks * 32 + q4 * 8);
      for (int j2 = 0; j2 < 8; j2++)
        bB[j2] = *(const bf16x8*)(&B2[((wn * 8 + j2) * 2 + ks) * 512 + lane * 8]);
      for (int i2 = 0; i2 < 2; i2++)
        for (int j2 = 0; j2 < 8; j2++)
          acc2[i2][j2] = __builtin_amdgcn_mfma_f32_16x16x32_bf16(aW[i2], bB[j2], acc2[i2][j2], 0, 0, 0);
    }
    // no barrier needed here: next q's K-loop barriers order B2 reads
    // before the next RT writes.
  }
  // epilogue: y[b][o][(J0+j')*64 + l0 + l_t]
  float* yb = y + (size_t)b * 64 * NKL;
  for (int i2 = 0; i2 < 2; i2++)
    for (int rr = 0; rr < 4; rr++) {
      int o = wm * 32 + i2 * 16 + q4 * 4 + rr;
      float bv = bias[o];
      for (int j2 = 0; j2 < 8; j2++) {
        int n2 = wn * 128 + j2 * 16 + r;
        int jp = n2 >> 2, l_t = n2 & 3;
        if (J0 + jp < NK)
          yb[(size_t)o * NKL + (J0 + jp) * 64 + l0 + l_t] = acc2[i2][j2][rr] + bv;
      }
    }
}

extern "C" void kernel_launch(void* const* d_in, const int* in_sizes, int n_in,
                              void* d_out, int out_size, void* d_ws, size_t ws_size,
                              hipStream_t stream) {
  const float* x = (const float*)d_in[0];
  const float* a0 = (const float*)d_in[1];
  const float* a1 = (const float*)d_in[2];
  const float* W = (const float*)d_in[3];
  const float* bias = (const float*)d_in[4];
  float* y = (float*)d_out;
  char* ws = (char*)d_ws;

  size_t off = 0;
  auto alloc = [&](size_t bytes) {
    size_t o = off;
    off = (off + bytes + 511) & ~(size_t)511;
    return o;
  };
  size_t o_xT  = alloc((size_t)NB * 4096 * KP * 2);
  size_t o_G   = alloc((size_t)NB * GROWS * KP * 2);
  size_t o_Ab  = alloc((size_t)NB * 2 * 256 * KP * 2);
  size_t o_At  = alloc((size_t)NB * 2 * 256 * KP * 2);
  size_t o_Wb  = alloc((size_t)64 * CIN * 2);

  u16* xT  = (u16*)(ws + o_xT);
  u16* G   = (u16*)(ws + o_G);
  u16* Abf = (u16*)(ws + o_Ab);
  u16* AbfT= (u16*)(ws + o_At);
  u16* Wbf = (u16*)(ws + o_Wb);

  k_prep_x<<<dim3(64, 16), 256, 0, stream>>>(x, xT);
  k_prep_A<<<dim3(8, 2, 16), 256, 0, stream>>>(a0, a1, Abf, AbfT, G);
  k_prep_I<<<dim3(416, 16), 256, 0, stream>>>(W, G, AbfT, Wbf);
  k_asq<<<dim3(4, 4, 32), 256, 0, stream>>>(Abf, AbfT, G);
  k_fused<<<dim3(1024), 256, 0, stream>>>(G, xT, Wbf, bias, y);
}

// Round 4
// 266.648 us; speedup vs baseline: 1.0280x; 1.0280x over previous
//
#include <hip/hip_runtime.h>

typedef unsigned short u16;
typedef __bf16 bf16x8 __attribute__((ext_vector_type(8)));
typedef float f32x4 __attribute__((ext_vector_type(4)));

// Problem constants (from reference)
#define NB 16      // batches
#define NC 64      // channels
#define NK 207     // nodes (K_DIM)
#define NL 64      // time (L_DIM)
#define KP 224     // padded GEMM K-dim over nodes (207 -> 224 = 7*32)
#define NKL 13248  // NK*NL
#define NROWP 13312 // padded (j,l) rows = 52*256
#define GROWS 1152 // stacked-G rows: 5*208 + 112 pad
#define CIN 320

__device__ __forceinline__ u16 f2bf(float f) {
  unsigned u = __builtin_bit_cast(unsigned, f);
  u += 0x7FFFu + ((u >> 16) & 1u);   // RNE; inputs are never NaN
  return (u16)(u >> 16);
}

// async global->LDS, 16 B per lane. ldst must be (wave-uniform base + lane*16).
__device__ __forceinline__ void g2l16(const u16* gsrc, u16* ldst) {
  __builtin_amdgcn_global_load_lds(
      (const __attribute__((address_space(1))) unsigned int*)gsrc,
      (__attribute__((address_space(3))) unsigned int*)ldst, 16, 0, 0);
}

#define XPAD 225   // odd fp32 stride: conflict-free column access

// ---- merged prep: one kernel, branch by block range (wave-uniform) ---------
// [0,1024)   : x (B,C,K*L) fp32 -> xT[b][(l*64+c)][k] bf16 (k-padded 224)
// [1024,1280): A -> Abf rows, AbfT cols (m0..m0+31), G q=1,3
// [1280,1312): G q=0 identity
// [1312,1328): G rows 1040..1151 zero
// [1328,1344): AbfT rows 224..255 zero
// 1344       : W -> bf16
__global__ __launch_bounds__(256) void k_prep_all(
    const float* __restrict__ x, const float* __restrict__ a0,
    const float* __restrict__ a1, const float* __restrict__ W,
    u16* __restrict__ xT, u16* __restrict__ Abf, u16* __restrict__ AbfT,
    u16* __restrict__ G, u16* __restrict__ Wbf) {
  __shared__ float lds[64 * XPAD];
  int id = blockIdx.x, t = threadIdx.x;
  if (id < 1024) {
    int c = id & 63, b = id >> 6;
    const float4* xp4 = (const float4*)(x + (size_t)(b * 64 + c) * NKL);
    for (int i4 = t; i4 < 3312; i4 += 256) {   // NKL/4; 4 consecutive l, same k
      float4 v = xp4[i4];
      int k = i4 >> 4, l0 = (i4 & 15) * 4;
      lds[(l0 + 0) * XPAD + k] = v.x;
      lds[(l0 + 1) * XPAD + k] = v.y;
      lds[(l0 + 2) * XPAD + k] = v.z;
      lds[(l0 + 3) * XPAD + k] = v.w;
    }
    __syncthreads();
    for (int ch = t; ch < 64 * 28; ch += 256) {
      int l = ch / 28, kc = ch - l * 28;
      u16 v[8] __attribute__((aligned(16)));
      for (int j = 0; j < 8; j++) {
        int k = kc * 8 + j;
        v[j] = (k < NK) ? f2bf(lds[l * XPAD + k]) : (u16)0;
      }
      *(int4*)(xT + ((size_t)b * 4096 + l * 64 + c) * KP + kc * 8) = *(int4*)v;
    }
  } else if (id < 1280) {
    int local = id - 1024;
    int rt = local & 7, w = (local >> 3) & 1, b = local >> 4;
    const float* A = (w ? a1 : a0) + (size_t)b * NK * NK;
    int m0 = rt * 32;
    for (int idx = t; idx < 32 * 224; idx += 256) {
      int r = idx / 224, k = idx - r * 224;
      int m = m0 + r;
      lds[r * XPAD + k] = (m < NK && k < NK) ? A[m * NK + k] : 0.f;
    }
    __syncthreads();
    for (int ch = t; ch < 32 * 28; ch += 256) {  // row-major: Abf + G q=1,3
      int rr = ch / 28, kc = ch - rr * 28;
      u16 v[8] __attribute__((aligned(16)));
      for (int j = 0; j < 8; j++) v[j] = f2bf(lds[rr * XPAD + kc * 8 + j]);
      int m = m0 + rr;
      *(int4*)(Abf + (((size_t)b * 2 + w) * 256 + m) * KP + kc * 8) = *(int4*)v;
      if (m < 208)
        *(int4*)(G + ((size_t)b * GROWS + (1 + 2 * w) * 208 + m) * KP + kc * 8) = *(int4*)v;
    }
    if (rt < 7) {                                // transpose: AbfT[n][m0+..]
      for (int ch = t; ch < 224 * 4; ch += 256) {
        int n = ch >> 2, mc = ch & 3;
        u16 v[8] __attribute__((aligned(16)));
        for (int j = 0; j < 8; j++) v[j] = f2bf(lds[(mc * 8 + j) * XPAD + n]);
        *(int4*)(AbfT + (((size_t)b * 2 + w) * 256 + n) * KP + m0 + mc * 8) = *(int4*)v;
      }
    }
  } else if (id < 1312) {
    int local = id - 1280, b = local >> 1, half = local & 1;
    for (int ci = t; ci < 104 * 28; ci += 256) {
      int jr = ci / 28, kc = ci - jr * 28;
      int j = half * 104 + jr;
      u16 v[8] __attribute__((aligned(16)));
      for (int jj = 0; jj < 8; jj++)
        v[jj] = (j == kc * 8 + jj && j < NK) ? (u16)0x3F80 : (u16)0;
      *(int4*)(G + ((size_t)b * GROWS + j) * KP + kc * 8) = *(int4*)v;
    }
  } else if (id < 1328) {
    int b = id - 1312;
    int4 z = {0, 0, 0, 0};
    int4* p = (int4*)(G + (size_t)b * GROWS * KP + (size_t)1040 * KP);
    for (int ci = t; ci < 3136; ci += 256) p[ci] = z;
  } else if (id < 1344) {
    int b = id - 1328;
    int4 z = {0, 0, 0, 0};
    for (int ci = t; ci < 1792; ci += 256) {
      int w = ci / 896, rem = ci - w * 896;
      *(int4*)(AbfT + (((size_t)b * 2 + w) * 256 + 224) * KP + rem * 8) = z;
    }
  } else {
    for (int ci = t; ci < 2560; ci += 256) {
      u16 v[8] __attribute__((aligned(16)));
      for (int j = 0; j < 8; j++) v[j] = f2bf(W[ci * 8 + j]);
      *(int4*)(Wbf + ci * 8) = *(int4*)v;
    }
  }
}

// ---- prep: A^2 via MFMA -> G blocks q=2,4 ----------------------------------
__global__ void k_asq(const u16* __restrict__ Abf, const u16* __restrict__ AbfT,
                      u16* __restrict__ G) {
  // grid (4 ntile, 4 mtile, 32=b*2+w), 256 threads, waves 2x2, wave tile 32x32
  int b = blockIdx.z >> 1, w = blockIdx.z & 1;
  int lane = threadIdx.x & 63, wave = threadIdx.x >> 6;
  int wm = wave >> 1, wn = wave & 1;
  const u16* Ab = Abf + ((size_t)b * 2 + w) * 256 * KP;
  const u16* At = AbfT + ((size_t)b * 2 + w) * 256 * KP;
  int m0 = blockIdx.y * 64 + wm * 32;
  int n0 = blockIdx.x * 64 + wn * 32;
  int r = lane & 15, q = lane >> 4;
  f32x4 acc[2][2] = {};
  for (int k0 = 0; k0 < KP; k0 += 32) {
    bf16x8 af[2], bg[2];
    for (int i = 0; i < 2; i++)
      af[i] = *(const bf16x8*)(Ab + (size_t)(m0 + i * 16 + r) * KP + k0 + q * 8);
    for (int i = 0; i < 2; i++)
      bg[i] = *(const bf16x8*)(At + (size_t)(n0 + i * 16 + r) * KP + k0 + q * 8);
    for (int i = 0; i < 2; i++)
      for (int j = 0; j < 2; j++)
        acc[i][j] = __builtin_amdgcn_mfma_f32_16x16x32_bf16(af[i], bg[j], acc[i][j], 0, 0, 0);
  }
  int qblk = 2 + 2 * w;
  for (int i = 0; i < 2; i++)
    for (int j = 0; j < 2; j++)
      for (int rr = 0; rr < 4; rr++) {
        int mj = m0 + i * 16 + q * 4 + rr;
        int nk = n0 + j * 16 + r;
        if (mj < 208 && nk < KP)
          G[((size_t)b * GROWS + qblk * 208 + mj) * KP + nk] = f2bf(acc[i][j][rr]);
      }
}

// ---- K1: H[(j,l)][(p,c)] = Gstack(1040x224) @ xT(4096x224)^T ---------------
__global__ __launch_bounds__(256) void k_diffuse(const u16* __restrict__ G,
                                                 const u16* __restrict__ xT,
                                                 u16* __restrict__ H, int b0) {
  // grid (32 ntile, 9 mtile, nc), 256 threads, waves 2x2, wave tile 64x64
  int bl = blockIdx.z;
  int b = b0 + bl;
  int lane = threadIdx.x & 63, wave = threadIdx.x >> 6;
  int wm = wave >> 1, wn = wave & 1;
  int m_wg = blockIdx.y * 128, n_wg = blockIdx.x * 128;
  const u16* Gb = G + (size_t)b * GROWS * KP;
  const u16* Xb = xT + (size_t)b * 4096 * KP;
  __shared__ __align__(16) u16 lds[16 * 512];  // 16 frag-tiles, 1KB each
  int r = lane & 15, q = lane >> 4;
  f32x4 acc[4][4] = {};
  const u16* src[4];
  u16* dst[4];
  for (int i = 0; i < 4; i++) {
    int t = wave * 4 + i;
    src[i] = (t < 8)
        ? Gb + (size_t)(m_wg + t * 16 + r) * KP + q * 8
        : Xb + (size_t)(n_wg + (t - 8) * 16 + r) * KP + q * 8;
    dst[i] = &lds[t * 512 + lane * 8];   // = wave-uniform base + lane*16B
  }
  for (int k0 = 0; k0 < KP; k0 += 32) {
    for (int i = 0; i < 4; i++) g2l16(src[i] + k0, dst[i]);
    __syncthreads();
    bf16x8 af[4], bg[4];
    for (int i = 0; i < 4; i++) af[i] = *(const bf16x8*)(&lds[(wm * 4 + i) * 512 + lane * 8]);
    for (int i = 0; i < 4; i++) bg[i] = *(const bf16x8*)(&lds[(8 + wn * 4 + i) * 512 + lane * 8]);
    for (int i = 0; i < 4; i++)
      for (int j = 0; j < 4; j++)
        acc[i][j] = __builtin_amdgcn_mfma_f32_16x16x32_bf16(af[i], bg[j], acc[i][j], 0, 0, 0);
    __syncthreads();
  }
  u16* Hb = H + (size_t)bl * NROWP * CIN;
  for (int i = 0; i < 4; i++)
    for (int rr = 0; rr < 4; rr++) {
      int m = m_wg + (wm * 4 + i) * 16 + q * 4 + rr;
      int qb = m / 208;
      int j = m - qb * 208;
      if (qb < 5 && j < NK) {
        for (int jj = 0; jj < 4; jj++) {
          int n = n_wg + (wn * 4 + jj) * 16 + r;
          int l = n >> 6, c = n & 63;
          Hb[(size_t)(j * 64 + l) * CIN + qb * 64 + c] = f2bf(acc[i][jj][rr]);
        }
      }
    }
}

// ---- K2: y = Wbf(64x320) @ H(13312x320)^T + bias ---------------------------
__global__ __launch_bounds__(256) void k_conv(const u16* __restrict__ Wbf,
                                              const u16* __restrict__ H,
                                              const float* __restrict__ bias,
                                              float* __restrict__ y, int b0) {
  // grid (52, 1, nc), 256 threads; WG tile 64x256; wave tile 64x64
  int bl = blockIdx.z, b = b0 + bl;
  int lane = threadIdx.x & 63, wave = threadIdx.x >> 6;
  int n_wgbase = blockIdx.x * 256;
  const u16* Hb = H + (size_t)bl * NROWP * CIN;
  __shared__ __align__(16) u16 lds[20 * 512];  // A tiles 0..3, B tiles 4..19
  int r = lane & 15, q = lane >> 4;
  f32x4 acc[4][4] = {};
  const u16* asrc = Wbf + (size_t)(wave * 16 + r) * CIN + q * 8;
  u16* adst = &lds[wave * 512 + lane * 8];
  const u16* bsrc[4];
  u16* bdst[4];
  for (int i = 0; i < 4; i++) {
    int nt = wave * 4 + i;
    bsrc[i] = Hb + (size_t)(n_wgbase + nt * 16 + r) * CIN + q * 8;
    bdst[i] = &lds[(4 + nt) * 512 + lane * 8];
  }
  for (int k0 = 0; k0 < CIN; k0 += 32) {
    g2l16(asrc + k0, adst);
    for (int i = 0; i < 4; i++) g2l16(bsrc[i] + k0, bdst[i]);
    __syncthreads();
    bf16x8 af[4], bg[4];
    for (int i = 0; i < 4; i++) af[i] = *(const bf16x8*)(&lds[i * 512 + lane * 8]);
    for (int i = 0; i < 4; i++) bg[i] = *(const bf16x8*)(&lds[(4 + wave * 4 + i) * 512 + lane * 8]);
    for (int i = 0; i < 4; i++)
      for (int j = 0; j < 4; j++)
        acc[i][j] = __builtin_amdgcn_mfma_f32_16x16x32_bf16(af[i], bg[j], acc[i][j], 0, 0, 0);
    __syncthreads();
  }
  float* yb = y + (size_t)b * 64 * NKL;
  for (int i = 0; i < 4; i++)
    for (int rr = 0; rr < 4; rr++) {
      int o = i * 16 + q * 4 + rr;
      float bv = bias[o];
      for (int j = 0; j < 4; j++) {
        int n = n_wgbase + wave * 64 + j * 16 + r;
        if (n < NKL) yb[(size_t)o * NKL + n] = acc[i][j][rr] + bv;
      }
    }
}

extern "C" void kernel_launch(void* const* d_in, const int* in_sizes, int n_in,
                              void* d_out, int out_size, void* d_ws, size_t ws_size,
                              hipStream_t stream) {
  const float* x = (const float*)d_in[0];
  const float* a0 = (const float*)d_in[1];
  const float* a1 = (const float*)d_in[2];
  const float* W = (const float*)d_in[3];
  const float* bias = (const float*)d_in[4];
  float* y = (float*)d_out;
  char* ws = (char*)d_ws;

  size_t off = 0;
  auto alloc = [&](size_t bytes) {
    size_t o = off;
    off = (off + bytes + 511) & ~(size_t)511;
    return o;
  };
  size_t o_xT  = alloc((size_t)NB * 4096 * KP * 2);
  size_t o_G   = alloc((size_t)NB * GROWS * KP * 2);
  size_t o_Ab  = alloc((size_t)NB * 2 * 256 * KP * 2);
  size_t o_At  = alloc((size_t)NB * 2 * 256 * KP * 2);
  size_t o_Wb  = alloc((size_t)64 * CIN * 2);
  size_t fixed = off;
  size_t per_h = (size_t)NROWP * CIN * 2;

  int nc = 16;
  while (nc > 1 && fixed + (size_t)nc * per_h > ws_size) nc >>= 1;
  size_t o_H = fixed;

  u16* xT  = (u16*)(ws + o_xT);
  u16* G   = (u16*)(ws + o_G);
  u16* Abf = (u16*)(ws + o_Ab);
  u16* AbfT= (u16*)(ws + o_At);
  u16* Wbf = (u16*)(ws + o_Wb);
  u16* H   = (u16*)(ws + o_H);

  k_prep_all<<<dim3(1345), 256, 0, stream>>>(x, a0, a1, W, xT, Abf, AbfT, G, Wbf);
  k_asq<<<dim3(4, 4, 32), 256, 0, stream>>>(Abf, AbfT, G);
  for (int c0 = 0; c0 < 16; c0 += nc) {
    k_diffuse<<<dim3(32, 9, nc), 256, 0, stream>>>(G, xT, H, c0);
    k_conv<<<dim3(52, 1, nc), 256, 0, stream>>>(Wbf, H, bias, y, c0);
  }
}